// Round 4
// baseline (224.022 us; speedup 1.0000x reference)
//
#include <hip/hip_runtime.h>
#include <math.h>

#define D_DIM 256
#define HW 16384
#define C 19
#define N_PX 131072
#define EPS 1e-8f

#define S_SC  1048576.0f       // 2^20 fixed point for class sums (|sum| < ~500)
#define IS_S  (1.0f/1048576.0f)
#define U_SC  16777216.0f      // 2^24 fixed point for unit-vector sums (|sum| < ~30)
#define IS_U  (1.0f/16777216.0f)

// ws layout in 4-byte words
#define OFF_S    0        // int[4864] class sums Σf, fixed-point
#define OFF_U    4864     // int[4864] class unit sums Σf/||f||, fixed-point
#define OFF_CNT  9728     // int[19]   class counts (+13 pad words to 9760)
#define WS_ZERO  9760
#define OFF_PART 9760     // int[512][9760] per-block partials (20 MB)
#define PSTRIDE  9760     // row stride, 16B-divisible
#define G1       512

// ---------- K1: single-pass, COALESCED pixel-major loads ----------
// grid 512 x 512 thr: block owns 256 px (2 rounds of 128). Wave w = tid>>6 owns
// channels [32w,32w+32); lane ln = tid&63 owns pixel pair 2ln,2ln+1. Every load
// is float2 at consecutive pixels -> 512 B contiguous per wave-op (round 1-3 had
// 64 scattered 16B gathers per wave-op; this is the single variable changed).
// Per-px norm = in-register 32-FMA per lane + 8-way cross-wave LDS combine
// (s_nfp stride 9 -> 2-way banks, free). Atomics: wave-uniform dd, per-lane
// labels (~7 same-addr passes) -> ~24 us DS-pipe/CU, overlapped with the ~21 us
// HBM stream on a different pipe at 16 waves/CU. sS atomics issue before the
// norm chain. k0 stays folded in (k1b is the only toucher of ws[0..WS_ZERO)).
__global__ __launch_bounds__(512, 4) void k1_pass(const float* __restrict__ in,
                                                  const int* __restrict__ tgt,
                                                  int* __restrict__ wsi) {
    __shared__ int sS[C * 257];
    __shared__ int sU[C * 257];
    __shared__ int s_cnt[C];
    __shared__ float s_nfp[128 * 9];   // [px_in_round][wave], stride 9
    const int tid = threadIdx.x;
    const int w   = tid >> 6;        // wave 0..7: channels 32w..32w+31
    const int ln  = tid & 63;        // lane: pixel pair 2ln, 2ln+1

    for (int i = tid; i < C * 257; i += 512) { sS[i] = 0; sU[i] = 0; }
    if (tid < C) s_cnt[tid] = 0;
    // folded k0: zero final accumulators (20 blocks x 512 words covers 9760)
    if (blockIdx.x < 20) {
        int i = (blockIdx.x << 9) + tid;
        if (i < WS_ZERO) wsi[i] = 0;
    }
    __syncthreads();

    const int px0 = blockIdx.x << 8;          // 256 px per block (64 blocks/image)
    const int b   = px0 >> 14;
    const float* bbase = in + (((size_t)(b * D_DIM + (w << 5))) << 14)
                            + (px0 & (HW - 1));

    #pragma unroll
    for (int r = 0; r < 2; ++r) {
        const int pp = (r << 7) + (ln << 1);   // pixel offset in block tile
        const int2 lab = *(const int2*)(tgt + px0 + pp);
        const int la = lab.x, lb = lab.y;
        if (w == 0) { atomicAdd(&s_cnt[la], 1); atomicAdd(&s_cnt[lb], 1); }

        // coalesced loads: 2 consecutive px x this wave's 32 channel planes
        float2 v[32];
        #pragma unroll
        for (int cc = 0; cc < 32; ++cc)
            v[cc] = *(const float2*)(bbase + ((size_t)cc << 14) + pp);

        const int rowa = la * 257, rowb = lb * 257;

        // sS atomics first: depend only on v, overlap the norm chain + barrier
        #pragma unroll
        for (int cc = 0; cc < 32; ++cc) {
            const int dd = (w << 5) + cc;
            atomicAdd(&sS[rowa + dd], __float2int_rn(v[cc].x * S_SC));
            atomicAdd(&sS[rowb + dd], __float2int_rn(v[cc].y * S_SC));
        }

        // per-px partial ||f||^2 over this wave's 32 channels (pure registers)
        float na = 0.f, nb = 0.f;
        #pragma unroll
        for (int cc = 0; cc < 32; ++cc) {
            na += v[cc].x * v[cc].x;
            nb += v[cc].y * v[cc].y;
        }
        s_nfp[(pp - (r << 7)) * 9 + w]     = na;   // row 2ln
        s_nfp[(pp - (r << 7) + 1) * 9 + w] = nb;   // row 2ln+1
        __syncthreads();
        float sumA = 0.f, sumB = 0.f;
        #pragma unroll
        for (int ww = 0; ww < 8; ++ww) {
            sumA += s_nfp[(ln << 1) * 9 + ww];
            sumB += ((ln << 1) + 1) * 9 + ww >= 0 ? s_nfp[((ln << 1) + 1) * 9 + ww] : 0.f;
        }
        const float sa = sumA > 0.f ? U_SC / sqrtf(sumA) : 0.f;
        const float sb = sumB > 0.f ? U_SC / sqrtf(sumB) : 0.f;

        #pragma unroll
        for (int cc = 0; cc < 32; ++cc) {
            const int dd = (w << 5) + cc;
            atomicAdd(&sU[rowa + dd], __float2int_rn(v[cc].x * sa));
            atomicAdd(&sU[rowb + dd], __float2int_rn(v[cc].y * sb));
        }
        __syncthreads();   // protect s_nfp before next round's writes
    }

    // plain coalesced writeout of this block's partial row (NO global atomics)
    int* __restrict__ row = wsi + OFF_PART + (size_t)blockIdx.x * PSTRIDE;
    for (int i = tid; i < C * 256; i += 512) {
        int c = i >> 8, d = i & 255;
        row[OFF_S + i] = sS[c * 257 + d];
        row[OFF_U + i] = sU[c * 257 + d];
    }
    if (tid < C)                 row[OFF_CNT + tid] = s_cnt[tid];
    else if (tid < 32)           row[OFF_CNT + tid] = 0;   // pad to 9760
}

// ---------- K1b: reduce 512 partial rows -> final arrays ----------
// grid (10, 32): block sums 16 rows for 1024 columns (int4), 4 atomics/thread to finish.
__global__ __launch_bounds__(256) void k1b_reduce(int* __restrict__ wsi) {
    const int col4 = blockIdx.x * 256 + threadIdx.x;     // int4 column index
    if (col4 >= PSTRIDE / 4) return;
    const int4* base = (const int4*)(wsi + OFF_PART)
                     + (size_t)blockIdx.y * 16 * (PSTRIDE / 4) + col4;
    int4 acc = {0, 0, 0, 0};
    #pragma unroll
    for (int r = 0; r < 16; ++r) {
        int4 v = base[(size_t)r * (PSTRIDE / 4)];
        acc.x += v.x; acc.y += v.y; acc.z += v.z; acc.w += v.w;
    }
    atomicAdd(&wsi[col4 * 4 + 0], acc.x);
    atomicAdd(&wsi[col4 * 4 + 1], acc.y);
    atomicAdd(&wsi[col4 * 4 + 2], acc.z);
    atomicAdd(&wsi[col4 * 4 + 3], acc.w);
}

// ---------- K2: centers, norms, Gram/diff, sim, final (1 block, 8 waves) ----------
__global__ __launch_bounds__(512) void k2_final(const int* __restrict__ wsi,
                                                float* __restrict__ out) {
    __shared__ __align__(16) float s_cen[C * 260];  // 260 = 65 float4: rows 16B-aligned
    __shared__ __align__(16) float s_u[C * 260];
    __shared__ float s_nc[C];
    __shared__ float s_cntf[C];
    __shared__ float s_pair[C * C];
    __shared__ float s_sim[C];
    const int tid = threadIdx.x;

    if (tid < C) s_cntf[tid] = (float)wsi[OFF_CNT + tid];
    __syncthreads();
    for (int i = tid; i < C * 256; i += 512) {
        int c = i >> 8, d = i & 255;
        float icnt = 1.f / fmaxf(s_cntf[c], 1.f);
        s_cen[c * 260 + d] = (float)wsi[OFF_S + i] * IS_S * icnt;
        s_u[c * 260 + d]   = (float)wsi[OFF_U + i] * IS_U;
    }
    __syncthreads();
    if (tid < C) {
        float nsq = 0.f;
        for (int d = 0; d < D_DIM; ++d) {
            float x = s_cen[tid * 260 + d];
            nsq += x * x;
        }
        s_nc[tid] = sqrtf(nsq);
    }
    __syncthreads();
    if (tid < C * C) {                       // waves 0-5: Gram + diff pairs
        int i = tid / C, j = tid % C;
        const float4* ci = (const float4*)&s_cen[i * 260];
        const float4* cj = (const float4*)&s_cen[j * 260];
        float dot = 0.f;
        #pragma unroll 8
        for (int k = 0; k < 64; ++k) {
            float4 a = ci[k], bb = cj[k];
            dot += a.x * bb.x + a.y * bb.y + a.z * bb.z + a.w * bb.w;
        }
        float S = dot / fmaxf(s_nc[i] * s_nc[j], EPS);
        s_pair[tid] = (i == j) ? (1.f - S) : fmaxf(S, 0.f);
    } else if (tid >= 384 && tid < 384 + C) { // wave 6: sim dots, concurrent with Gram
        int i = tid - 384;
        const float4* ci = (const float4*)&s_cen[i * 260];
        const float4* ui = (const float4*)&s_u[i * 260];
        float dot = 0.f;
        #pragma unroll 8
        for (int k = 0; k < 64; ++k) {
            float4 a = ci[k], bb = ui[k];
            dot += a.x * bb.x + a.y * bb.y + a.z * bb.z + a.w * bb.w;
        }
        // sim_i = 1 - (Σ cos)/cnt = 1 - dot(center,U)/(nc*cnt)
        s_sim[i] = (s_cntf[i] > 0.f)
                 ? (1.f - dot / fmaxf(s_nc[i] * s_cntf[i], EPS)) : 0.f;
    }
    __syncthreads();
    if (tid < C) {
        float row = 0.f;
        for (int j = 0; j < C; ++j) row += s_pair[tid * C + j];
        s_pair[tid * C] = (s_cntf[tid] > 0.f) ? (row * (1.f / (float)C)) : 0.f;
    }
    __syncthreads();
    if (tid == 0) {
        float tot = 0.f;
        for (int i = 0; i < C; ++i) tot += s_pair[i * C] + s_sim[i];
        out[0] = tot;
    }
}

extern "C" void kernel_launch(void* const* d_in, const int* in_sizes, int n_in,
                              void* d_out, int out_size, void* d_ws, size_t ws_size,
                              hipStream_t stream) {
    const float* in  = (const float*)d_in[0];
    const int*   tgt = (const int*)d_in[1];
    float* out = (float*)d_out;
    int*   wsi = (int*)d_ws;

    k1_pass<<<G1, 512, 0, stream>>>(in, tgt, wsi);
    k1b_reduce<<<dim3(10, 32), 256, 0, stream>>>(wsi);
    k2_final<<<1, 512, 0, stream>>>(wsi, out);
}

// Round 5
// 216.193 us; speedup vs baseline: 1.0362x; 1.0362x over previous
//
#include <hip/hip_runtime.h>
#include <math.h>

#define D_DIM 256
#define HW 16384
#define C 19
#define N_PX 131072
#define EPS 1e-8f

#define S_SC  1048576.0f       // 2^20 fixed point for class sums (|sum| < ~500)
#define IS_S  (1.0f/1048576.0f)
#define U_SC  16777216.0f      // 2^24 fixed point for unit-vector sums (|sum| < ~30)
#define IS_U  (1.0f/16777216.0f)

// ws layout in 4-byte words
#define OFF_S    0        // int[4864] class sums Σf, fixed-point
#define OFF_U    4864     // int[4864] class unit sums Σf/||f||, fixed-point
#define OFF_CNT  9728     // int[19]   class counts (+13 pad words to 9760)
#define WS_ZERO  9760
#define OFF_PART 9760     // int[512][9760] per-block partials (20 MB)
#define PSTRIDE  9760     // row stride, 16B-divisible
#define G1       512
#define TPX      32       // tile pixels

// ---------- K1: LDS-pivot — coalesced loads AND collision-free atomics ----------
// grid 512 x 512 thr, 8 tiles of 32 px per block. Per tile:
//  A) load pixel-major: lane = (plane-sub lg = ln>>3, px-chunk pxo = (ln&7)*4);
//     per wave-op 8 planes x 128 contiguous B (full 64B lines, no partial-line
//     traffic — rounds 1-3 issued 64 scattered 16B requests per wave-op).
//     Norm partials in registers + 3 shfl_xor over lg; stage tile to
//     ldsT[px][ch] stride 257 (bank = (4(ln&7)+j+8g+lg)&31: exact 2-way, free).
//  B) 32 threads finalize per-px norms -> s_scale.
//  C) wave w owns px w*4..w*4+3: WAVE-UNIFORM label, lane = channel g2*64+ln.
//     Zero same-address collisions (distinct ch), bank = (lab+ch)&31 exact
//     2-way. This is the property no prior round had simultaneously with
//     coalesced loads. LDS 73.4 KB -> 2 blocks/CU.
// sS ints bit-identical to all prior rounds (same __float2int_rn per element).
__global__ __launch_bounds__(512, 2) void k1_pass(const float* __restrict__ in,
                                                  const int* __restrict__ tgt,
                                                  int* __restrict__ wsi) {
    __shared__ int   sS[C * 257];
    __shared__ int   sU[C * 257];
    __shared__ int   s_cnt[C];
    __shared__ float ldsT[TPX * 257];   // [px][ch], stride 257
    __shared__ float s_nfp[TPX * 9];    // [px][wave]
    __shared__ float s_scale[TPX];
    __shared__ int   s_lab[TPX];
    const int tid = threadIdx.x;
    const int w   = tid >> 6;          // wave 0..7
    const int ln  = tid & 63;
    const int lg  = ln >> 3;           // plane sub-lane 0..7
    const int pxo = (ln & 7) << 2;     // px chunk base 0,4,...,28

    for (int i = tid; i < C * 257; i += 512) { sS[i] = 0; sU[i] = 0; }
    if (tid < C) s_cnt[tid] = 0;
    // folded k0: zero final accumulators (20 blocks x 512 words covers 9760)
    if (blockIdx.x < 20) {
        int i = (blockIdx.x << 9) + tid;
        if (i < WS_ZERO) wsi[i] = 0;
    }
    __syncthreads();

    const int px0 = blockIdx.x << 8;   // 256 px per block (64 blocks/image)
    const int b   = px0 >> 14;

    #pragma unroll 1
    for (int t = 0; t < 8; ++t) {
        const int P  = px0 + (t << 5);             // tile global px base
        const int hw = (P & (HW - 1)) + pxo;       // in-plane offset for lane

        // ---- phase A: labels/counts, coalesced load, norms, stage ----
        if (tid < TPX) {
            const int lab = tgt[P + tid];
            s_lab[tid] = lab;
            atomicAdd(&s_cnt[lab], 1);
        }
        float4 v[4];
        #pragma unroll
        for (int g = 0; g < 4; ++g) {
            const int pl = (w << 5) + (g << 3) + lg;   // this thread's plane
            v[g] = *(const float4*)(in + (((size_t)(b * D_DIM + pl)) << 14) + hw);
        }
        #pragma unroll
        for (int g = 0; g < 4; ++g) {
            const int pl = (w << 5) + (g << 3) + lg;
            ldsT[(pxo + 0) * 257 + pl] = v[g].x;
            ldsT[(pxo + 1) * 257 + pl] = v[g].y;
            ldsT[(pxo + 2) * 257 + pl] = v[g].z;
            ldsT[(pxo + 3) * 257 + pl] = v[g].w;
        }
        // per-px norm partial over this thread's 4 planes
        float n0 = v[0].x*v[0].x + v[1].x*v[1].x + v[2].x*v[2].x + v[3].x*v[3].x;
        float n1 = v[0].y*v[0].y + v[1].y*v[1].y + v[2].y*v[2].y + v[3].y*v[3].y;
        float n2 = v[0].z*v[0].z + v[1].z*v[1].z + v[2].z*v[2].z + v[3].z*v[3].z;
        float n3 = v[0].w*v[0].w + v[1].w*v[1].w + v[2].w*v[2].w + v[3].w*v[3].w;
        // reduce across lg (lane bits 3,4,5) -> sum over wave's 32 planes
        #pragma unroll
        for (int m = 8; m <= 32; m <<= 1) {
            n0 += __shfl_xor(n0, m, 64);
            n1 += __shfl_xor(n1, m, 64);
            n2 += __shfl_xor(n2, m, 64);
            n3 += __shfl_xor(n3, m, 64);
        }
        if (lg == 0) {
            s_nfp[(pxo + 0) * 9 + w] = n0;
            s_nfp[(pxo + 1) * 9 + w] = n1;
            s_nfp[(pxo + 2) * 9 + w] = n2;
            s_nfp[(pxo + 3) * 9 + w] = n3;
        }
        __syncthreads();

        // ---- phase B: finalize norms ----
        if (tid < TPX) {
            float nf = 0.f;
            #pragma unroll
            for (int ww = 0; ww < 8; ++ww) nf += s_nfp[tid * 9 + ww];
            s_scale[tid] = nf > 0.f ? U_SC / sqrtf(nf) : 0.f;
        }
        __syncthreads();

        // ---- phase C: wave-uniform-label atomics, lane = channel ----
        #pragma unroll
        for (int k = 0; k < 4; ++k) {
            const int   lp  = (w << 2) + k;        // local px 0..31
            const int   lab = s_lab[lp];           // wave-uniform
            const float sc  = s_scale[lp];
            const int   rowc = lab * 257;
            #pragma unroll
            for (int g2 = 0; g2 < 4; ++g2) {
                const int   ch  = (g2 << 6) + ln;
                const float val = ldsT[lp * 257 + ch];
                atomicAdd(&sS[rowc + ch], __float2int_rn(val * S_SC));
                atomicAdd(&sU[rowc + ch], __float2int_rn(val * sc));
            }
        }
        __syncthreads();   // protect ldsT/s_nfp/s_lab before next tile
    }

    // plain coalesced writeout of this block's partial row (NO global atomics)
    int* __restrict__ row = wsi + OFF_PART + (size_t)blockIdx.x * PSTRIDE;
    for (int i = tid; i < C * 256; i += 512) {
        int c = i >> 8, d = i & 255;
        row[OFF_S + i] = sS[c * 257 + d];
        row[OFF_U + i] = sU[c * 257 + d];
    }
    if (tid < C)                 row[OFF_CNT + tid] = s_cnt[tid];
    else if (tid < 32)           row[OFF_CNT + tid] = 0;   // pad to 9760
}

// ---------- K1b: reduce 512 partial rows -> final arrays ----------
// grid (10, 32): block sums 16 rows for 1024 columns (int4), 4 atomics/thread to finish.
__global__ __launch_bounds__(256) void k1b_reduce(int* __restrict__ wsi) {
    const int col4 = blockIdx.x * 256 + threadIdx.x;     // int4 column index
    if (col4 >= PSTRIDE / 4) return;
    const int4* base = (const int4*)(wsi + OFF_PART)
                     + (size_t)blockIdx.y * 16 * (PSTRIDE / 4) + col4;
    int4 acc = {0, 0, 0, 0};
    #pragma unroll
    for (int r = 0; r < 16; ++r) {
        int4 v = base[(size_t)r * (PSTRIDE / 4)];
        acc.x += v.x; acc.y += v.y; acc.z += v.z; acc.w += v.w;
    }
    atomicAdd(&wsi[col4 * 4 + 0], acc.x);
    atomicAdd(&wsi[col4 * 4 + 1], acc.y);
    atomicAdd(&wsi[col4 * 4 + 2], acc.z);
    atomicAdd(&wsi[col4 * 4 + 3], acc.w);
}

// ---------- K2: centers, norms, Gram/diff, sim, final (1 block, 8 waves) ----------
__global__ __launch_bounds__(512) void k2_final(const int* __restrict__ wsi,
                                                float* __restrict__ out) {
    __shared__ __align__(16) float s_cen[C * 260];  // 260 = 65 float4: rows 16B-aligned
    __shared__ __align__(16) float s_u[C * 260];
    __shared__ float s_nc[C];
    __shared__ float s_cntf[C];
    __shared__ float s_pair[C * C];
    __shared__ float s_sim[C];
    const int tid = threadIdx.x;

    if (tid < C) s_cntf[tid] = (float)wsi[OFF_CNT + tid];
    __syncthreads();
    for (int i = tid; i < C * 256; i += 512) {
        int c = i >> 8, d = i & 255;
        float icnt = 1.f / fmaxf(s_cntf[c], 1.f);
        s_cen[c * 260 + d] = (float)wsi[OFF_S + i] * IS_S * icnt;
        s_u[c * 260 + d]   = (float)wsi[OFF_U + i] * IS_U;
    }
    __syncthreads();
    if (tid < C) {
        float nsq = 0.f;
        for (int d = 0; d < D_DIM; ++d) {
            float x = s_cen[tid * 260 + d];
            nsq += x * x;
        }
        s_nc[tid] = sqrtf(nsq);
    }
    __syncthreads();
    if (tid < C * C) {                       // waves 0-5: Gram + diff pairs
        int i = tid / C, j = tid % C;
        const float4* ci = (const float4*)&s_cen[i * 260];
        const float4* cj = (const float4*)&s_cen[j * 260];
        float dot = 0.f;
        #pragma unroll 8
        for (int k = 0; k < 64; ++k) {
            float4 a = ci[k], bb = cj[k];
            dot += a.x * bb.x + a.y * bb.y + a.z * bb.z + a.w * bb.w;
        }
        float S = dot / fmaxf(s_nc[i] * s_nc[j], EPS);
        s_pair[tid] = (i == j) ? (1.f - S) : fmaxf(S, 0.f);
    } else if (tid >= 384 && tid < 384 + C) { // wave 6: sim dots, concurrent with Gram
        int i = tid - 384;
        const float4* ci = (const float4*)&s_cen[i * 260];
        const float4* ui = (const float4*)&s_u[i * 260];
        float dot = 0.f;
        #pragma unroll 8
        for (int k = 0; k < 64; ++k) {
            float4 a = ci[k], bb = ui[k];
            dot += a.x * bb.x + a.y * bb.y + a.z * bb.z + a.w * bb.w;
        }
        // sim_i = 1 - (Σ cos)/cnt = 1 - dot(center,U)/(nc*cnt)
        s_sim[i] = (s_cntf[i] > 0.f)
                 ? (1.f - dot / fmaxf(s_nc[i] * s_cntf[i], EPS)) : 0.f;
    }
    __syncthreads();
    if (tid < C) {
        float row = 0.f;
        for (int j = 0; j < C; ++j) row += s_pair[tid * C + j];
        s_pair[tid * C] = (s_cntf[tid] > 0.f) ? (row * (1.f / (float)C)) : 0.f;
    }
    __syncthreads();
    if (tid == 0) {
        float tot = 0.f;
        for (int i = 0; i < C; ++i) tot += s_pair[i * C] + s_sim[i];
        out[0] = tot;
    }
}

extern "C" void kernel_launch(void* const* d_in, const int* in_sizes, int n_in,
                              void* d_out, int out_size, void* d_ws, size_t ws_size,
                              hipStream_t stream) {
    const float* in  = (const float*)d_in[0];
    const int*   tgt = (const int*)d_in[1];
    float* out = (float*)d_out;
    int*   wsi = (int*)d_ws;

    k1_pass<<<G1, 512, 0, stream>>>(in, tgt, wsi);
    k1b_reduce<<<dim3(10, 32), 256, 0, stream>>>(wsi);
    k2_final<<<1, 512, 0, stream>>>(wsi, out);
}

// Round 6
// 214.588 us; speedup vs baseline: 1.0440x; 1.0075x over previous
//
#include <hip/hip_runtime.h>
#include <math.h>

#define D_DIM 256
#define HW 16384
#define C 19
#define N_PX 131072
#define EPS 1e-8f

#define S_SC  1048576.0f       // 2^20 fixed point for class sums (|sum| < ~500)
#define IS_S  (1.0f/1048576.0f)
#define U_SC  16777216.0f      // 2^24 fixed point for unit-vector sums (|sum| < ~30)
#define IS_U  (1.0f/16777216.0f)

// ws layout in 4-byte words
#define OFF_S    0        // int[4864] class sums Σf, fixed-point
#define OFF_U    4864     // int[4864] class unit sums Σf/||f||, fixed-point
#define OFF_CNT  9728     // int[19]   class counts (+pad to 9760)
#define TICKET   9759     // last-block ticket: in zeroed pad zone, only +0 from reduce
#define WS_ZERO  9760
#define OFF_PART 9760     // int[256][9760] per-block partials (10 MB)
#define PSTRIDE  9760     // row stride, 16B-divisible
#define G1       256      // 512 px per block

#define TPX      32       // tile pixels

// coherent read of a device-scope-atomically-written word (cross-XCD safe)
__device__ __forceinline__ int aload(int* p) { return atomicAdd(p, 0); }

// ---------- K1: LDS-pivot (R5 structure, proven at HBM floor), 512 px/block ----------
// grid 256 x 512 thr, 16 tiles of 32 px. Per tile:
//  A) coalesced pixel-major load (8 planes x 128 contiguous B per wave-op),
//     norm partials in regs + 3 shfl_xor, stage to ldsT[px][ch] stride 257.
//  B) 32 threads finalize per-px norms.
//  C) wave w owns px w*4..w*4+3: wave-uniform label, lane = channel -> zero
//     same-address collisions, exact 2-way banks (free).
// G1=256 halves partial writeout vs prior rounds; k1 stream time unchanged.
__global__ __launch_bounds__(512, 2) void k1_pass(const float* __restrict__ in,
                                                  const int* __restrict__ tgt,
                                                  int* __restrict__ wsi) {
    __shared__ int   sS[C * 257];
    __shared__ int   sU[C * 257];
    __shared__ int   s_cnt[C];
    __shared__ float ldsT[TPX * 257];   // [px][ch], stride 257
    __shared__ float s_nfp[TPX * 9];    // [px][wave]
    __shared__ float s_scale[TPX];
    __shared__ int   s_lab[TPX];
    const int tid = threadIdx.x;
    const int w   = tid >> 6;          // wave 0..7
    const int ln  = tid & 63;
    const int lg  = ln >> 3;           // plane sub-lane 0..7
    const int pxo = (ln & 7) << 2;     // px chunk base 0,4,...,28

    for (int i = tid; i < C * 257; i += 512) { sS[i] = 0; sU[i] = 0; }
    if (tid < C) s_cnt[tid] = 0;
    // folded k0: zero final accumulators + ticket (20 blocks x 512 words >= 9760)
    if (blockIdx.x < 20) {
        int i = (blockIdx.x << 9) + tid;
        if (i < WS_ZERO) wsi[i] = 0;
    }
    __syncthreads();

    const int px0 = blockIdx.x << 9;   // 512 px per block (32 blocks/image)
    const int b   = px0 >> 14;

    #pragma unroll 1
    for (int t = 0; t < 16; ++t) {
        const int P  = px0 + (t << 5);             // tile global px base
        const int hw = (P & (HW - 1)) + pxo;       // in-plane offset for lane

        // ---- phase A: labels/counts, coalesced load, norms, stage ----
        if (tid < TPX) {
            const int lab = tgt[P + tid];
            s_lab[tid] = lab;
            atomicAdd(&s_cnt[lab], 1);
        }
        float4 v[4];
        #pragma unroll
        for (int g = 0; g < 4; ++g) {
            const int pl = (w << 5) + (g << 3) + lg;   // this thread's plane
            v[g] = *(const float4*)(in + (((size_t)(b * D_DIM + pl)) << 14) + hw);
        }
        #pragma unroll
        for (int g = 0; g < 4; ++g) {
            const int pl = (w << 5) + (g << 3) + lg;
            ldsT[(pxo + 0) * 257 + pl] = v[g].x;
            ldsT[(pxo + 1) * 257 + pl] = v[g].y;
            ldsT[(pxo + 2) * 257 + pl] = v[g].z;
            ldsT[(pxo + 3) * 257 + pl] = v[g].w;
        }
        float n0 = v[0].x*v[0].x + v[1].x*v[1].x + v[2].x*v[2].x + v[3].x*v[3].x;
        float n1 = v[0].y*v[0].y + v[1].y*v[1].y + v[2].y*v[2].y + v[3].y*v[3].y;
        float n2 = v[0].z*v[0].z + v[1].z*v[1].z + v[2].z*v[2].z + v[3].z*v[3].z;
        float n3 = v[0].w*v[0].w + v[1].w*v[1].w + v[2].w*v[2].w + v[3].w*v[3].w;
        #pragma unroll
        for (int m = 8; m <= 32; m <<= 1) {
            n0 += __shfl_xor(n0, m, 64);
            n1 += __shfl_xor(n1, m, 64);
            n2 += __shfl_xor(n2, m, 64);
            n3 += __shfl_xor(n3, m, 64);
        }
        if (lg == 0) {
            s_nfp[(pxo + 0) * 9 + w] = n0;
            s_nfp[(pxo + 1) * 9 + w] = n1;
            s_nfp[(pxo + 2) * 9 + w] = n2;
            s_nfp[(pxo + 3) * 9 + w] = n3;
        }
        __syncthreads();

        // ---- phase B: finalize norms ----
        if (tid < TPX) {
            float nf = 0.f;
            #pragma unroll
            for (int ww = 0; ww < 8; ++ww) nf += s_nfp[tid * 9 + ww];
            s_scale[tid] = nf > 0.f ? U_SC / sqrtf(nf) : 0.f;
        }
        __syncthreads();

        // ---- phase C: wave-uniform-label atomics, lane = channel ----
        #pragma unroll
        for (int k = 0; k < 4; ++k) {
            const int   lp  = (w << 2) + k;        // local px 0..31
            const int   lab = s_lab[lp];           // wave-uniform
            const float sc  = s_scale[lp];
            const int   rowc = lab * 257;
            #pragma unroll
            for (int g2 = 0; g2 < 4; ++g2) {
                const int   ch  = (g2 << 6) + ln;
                const float val = ldsT[lp * 257 + ch];
                atomicAdd(&sS[rowc + ch], __float2int_rn(val * S_SC));
                atomicAdd(&sU[rowc + ch], __float2int_rn(val * sc));
            }
        }
        __syncthreads();   // protect ldsT/s_nfp/s_lab before next tile
    }

    // plain coalesced writeout of this block's partial row (NO global atomics)
    int* __restrict__ row = wsi + OFF_PART + (size_t)blockIdx.x * PSTRIDE;
    for (int i = tid; i < C * 256; i += 512) {
        int c = i >> 8, d = i & 255;
        row[OFF_S + i] = sS[c * 257 + d];
        row[OFF_U + i] = sU[c * 257 + d];
    }
    if (tid < C)                 row[OFF_CNT + tid] = s_cnt[tid];
    else if (tid < 32)           row[OFF_CNT + tid] = 0;   // pad to 9760
}

// ---------- K1b+K2 fused: reduce 256 partial rows -> final, last block finishes ----------
// grid (5,16) = 80 blocks x 512 thr. Each block sums 16 rows x 512 int4-cols and
// atomically adds into the final arrays. Then: __syncthreads() (compiler drains
// vmcnt -> this block's atomics are at the coherent point), __threadfence(),
// tid0 takes a ticket; the 80th block re-reads the final arrays with atomicAdd(p,0)
// coherent loads (cross-XCD safe, G16) and computes centers/Gram/sim/output.
__global__ __launch_bounds__(512) void k1b_k2(int* __restrict__ wsi,
                                              float* __restrict__ out) {
    __shared__ __align__(16) float s_cen[C * 260];  // 260 = 65 float4
    __shared__ __align__(16) float s_u[C * 260];
    __shared__ float s_nc[C];
    __shared__ float s_cntf[C];
    __shared__ float s_pair[C * C];
    __shared__ float s_sim[C];
    __shared__ int   s_last;
    const int tid  = threadIdx.x;
    const int col4 = blockIdx.x * 512 + tid;     // int4 column index

    if (col4 < PSTRIDE / 4) {
        const int4* base = (const int4*)(wsi + OFF_PART)
                         + (size_t)blockIdx.y * 16 * (PSTRIDE / 4) + col4;
        int4 acc = {0, 0, 0, 0};
        #pragma unroll
        for (int r = 0; r < 16; ++r) {
            int4 v = base[(size_t)r * (PSTRIDE / 4)];
            acc.x += v.x; acc.y += v.y; acc.z += v.z; acc.w += v.w;
        }
        atomicAdd(&wsi[col4 * 4 + 0], acc.x);
        atomicAdd(&wsi[col4 * 4 + 1], acc.y);
        atomicAdd(&wsi[col4 * 4 + 2], acc.z);
        atomicAdd(&wsi[col4 * 4 + 3], acc.w);
    }
    __syncthreads();                    // all this block's atomics drained (vmcnt 0)
    if (tid == 0) {
        __threadfence();
        int t = atomicAdd(&wsi[TICKET], 1);   // ticket word only ever receives +0 from cols
        s_last = (t == (int)(gridDim.x * gridDim.y) - 1);
    }
    __syncthreads();
    if (!s_last) return;

    // ---- k2 body (last block only; coherent reads) ----
    if (tid < C) s_cntf[tid] = (float)aload(&wsi[OFF_CNT + tid]);
    __syncthreads();
    for (int i = tid; i < C * 256; i += 512) {
        int c = i >> 8, d = i & 255;
        float icnt = 1.f / fmaxf(s_cntf[c], 1.f);
        s_cen[c * 260 + d] = (float)aload(&wsi[OFF_S + i]) * IS_S * icnt;
        s_u[c * 260 + d]   = (float)aload(&wsi[OFF_U + i]) * IS_U;
    }
    __syncthreads();
    if (tid < C) {
        float nsq = 0.f;
        for (int d = 0; d < D_DIM; ++d) {
            float x = s_cen[tid * 260 + d];
            nsq += x * x;
        }
        s_nc[tid] = sqrtf(nsq);
    }
    __syncthreads();
    if (tid < C * C) {                       // waves 0-5: Gram + diff pairs
        int i = tid / C, j = tid % C;
        const float4* ci = (const float4*)&s_cen[i * 260];
        const float4* cj = (const float4*)&s_cen[j * 260];
        float dot = 0.f;
        #pragma unroll 8
        for (int k = 0; k < 64; ++k) {
            float4 a = ci[k], bb = cj[k];
            dot += a.x * bb.x + a.y * bb.y + a.z * bb.z + a.w * bb.w;
        }
        float S = dot / fmaxf(s_nc[i] * s_nc[j], EPS);
        s_pair[tid] = (i == j) ? (1.f - S) : fmaxf(S, 0.f);
    } else if (tid >= 384 && tid < 384 + C) { // wave 6: sim dots, concurrent with Gram
        int i = tid - 384;
        const float4* ci = (const float4*)&s_cen[i * 260];
        const float4* ui = (const float4*)&s_u[i * 260];
        float dot = 0.f;
        #pragma unroll 8
        for (int k = 0; k < 64; ++k) {
            float4 a = ci[k], bb = ui[k];
            dot += a.x * bb.x + a.y * bb.y + a.z * bb.z + a.w * bb.w;
        }
        // sim_i = 1 - (Σ cos)/cnt = 1 - dot(center,U)/(nc*cnt)
        s_sim[i] = (s_cntf[i] > 0.f)
                 ? (1.f - dot / fmaxf(s_nc[i] * s_cntf[i], EPS)) : 0.f;
    }
    __syncthreads();
    if (tid < C) {
        float row = 0.f;
        for (int j = 0; j < C; ++j) row += s_pair[tid * C + j];
        s_pair[tid * C] = (s_cntf[tid] > 0.f) ? (row * (1.f / (float)C)) : 0.f;
    }
    __syncthreads();
    if (tid == 0) {
        float tot = 0.f;
        for (int i = 0; i < C; ++i) tot += s_pair[i * C] + s_sim[i];
        out[0] = tot;
    }
}

extern "C" void kernel_launch(void* const* d_in, const int* in_sizes, int n_in,
                              void* d_out, int out_size, void* d_ws, size_t ws_size,
                              hipStream_t stream) {
    const float* in  = (const float*)d_in[0];
    const int*   tgt = (const int*)d_in[1];
    float* out = (float*)d_out;
    int*   wsi = (int*)d_ws;

    k1_pass<<<G1, 512, 0, stream>>>(in, tgt, wsi);
    k1b_k2<<<dim3(5, 16), 512, 0, stream>>>(wsi, out);
}